// Round 22
// baseline (117.555 us; speedup 1.0000x reference)
//
#include <hip/hip_runtime.h>

#define IN_F 1024
#define OUT_F 1024
#define NNZ 16384

typedef _Float16 f16;
typedef _Float16 f16x8 __attribute__((ext_vector_type(8)));
typedef float f32x4 __attribute__((ext_vector_type(4)));
typedef unsigned short ushort8 __attribute__((ext_vector_type(8)));

#define AS1 __attribute__((address_space(1)))
#define AS3 __attribute__((address_space(3)))

// ---------------------------------------------------------------------------
// r22: gemm15 = gemm12's f16 LDS geometry + in-kernel A conversion.
// A-path: reg-staged convert (8x float4 global loads issued FIRST in the
// tile; cvt + 4x ds_write_b128 AFTER the MFMA clusters -> T14 issue-early/
// write-late, ~1-tile flight). A LDS stays f16 at the proven swizzled layout
// (reg-staging can scatter) -> LDS read traffic = gemm12, no conv pass.
// B: pure DMA, TRIPLE-buffered distance-2 (B(KT+2) issued at KT; gate VMW(4)
// keeps it in flight). LDS 160 KiB = A 2x32K + B 3x32K.
// Queue trace: [B(KT+1) | A-loads(8) | B(KT+2)] -> compiler cvt-wait ==
// vmcnt(4) (drains A, keeps B(KT+2)); gate: lgkm(0) (ds_writes!) + VMW(4)
// -> s_barrier -> SB0.  SYNC INVARIANT (r9) holds for B (DMA) via the gate;
// A's cross-wave visibility via lgkm(0)+barrier.
// Workspace: Wl = LINEAR W_eff (2 MiB) @0.
// ---------------------------------------------------------------------------

__device__ __forceinline__ int compute_mode(const unsigned short* __restrict__ w,
                                            float* smax, int* semax) {
  int t = threadIdx.x;
  const float* wf = (const float*)w;
  float m32 = fmaxf(fabsf(wf[t]), fabsf(wf[t + 256]));
  int e8 = 0;
#pragma unroll
  for (int j = 0; j < 8; ++j) {
    unsigned short u = w[t * 8 + j];
    int e = (u >> 7) & 0xFF;
    e8 = e > e8 ? e : e8;
  }
  smax[t] = m32; semax[t] = e8;
  __syncthreads();
  for (int s = 128; s > 0; s >>= 1) {
    if (t < s) {
      smax[t] = fmaxf(smax[t], smax[t + s]);
      semax[t] = semax[t] > semax[t + s] ? semax[t] : semax[t + s];
    }
    __syncthreads();
  }
  int m;
  if (!(smax[0] > 1e-6f)) m = 2;        // native f16
  else if (semax[0] >= 140) m = 0;      // f32-upcast
  else m = 1;                           // bf16
  return m;
}

__device__ __forceinline__ float load_w(const void* base, size_t i, int mode) {
  if (mode == 0) return ((const float*)base)[i];
  if (mode == 1) {
    unsigned int u = (unsigned int)((const unsigned short*)base)[i] << 16;
    return __uint_as_float(u);
  }
  return (float)((const f16*)base)[i];
}

__global__ void prep_base(const void* __restrict__ base, f16* __restrict__ Wl) {
  __shared__ float smax[256];
  __shared__ int semax[256];
  int mode = compute_mode((const unsigned short*)base, smax, semax);
  int id = blockIdx.x * 256 + threadIdx.x;
  size_t off = (size_t)id * 8;
  f16x8 h;
  if (mode == 0) {
    const float* b = (const float*)base + off;
    float4 v0 = *reinterpret_cast<const float4*>(b);
    float4 v1 = *reinterpret_cast<const float4*>(b + 4);
    h = (f16x8){(f16)v0.x, (f16)v0.y, (f16)v0.z, (f16)v0.w,
                (f16)v1.x, (f16)v1.y, (f16)v1.z, (f16)v1.w};
  } else if (mode == 1) {
    ushort8 uv = *reinterpret_cast<const ushort8*>((const unsigned short*)base + off);
#pragma unroll
    for (int j = 0; j < 8; ++j)
      h[j] = (f16)__uint_as_float((unsigned int)uv[j] << 16);
  } else {
    h = *reinterpret_cast<const f16x8*>((const f16*)base + off);
  }
  *reinterpret_cast<f16x8*>(Wl + off) = h;
}

__global__ void prep_scatter(const void* __restrict__ base,
                             const void* __restrict__ vals,
                             const int* __restrict__ idx,
                             const float* __restrict__ alpha,
                             f16* __restrict__ Wl) {
  __shared__ float smax[256];
  __shared__ int semax[256];
  int mode = compute_mode((const unsigned short*)base, smax, semax);
  int i = blockIdx.x * 256 + threadIdx.x;
  if (i >= NNZ) return;
  int id = idx[i];
  float v = load_w(base, id, mode) + alpha[0] * load_w(vals, i, mode);
  Wl[id] = (f16)v;
}

#define SB0 __builtin_amdgcn_sched_barrier(0)
#define VMW(N) asm volatile("s_waitcnt vmcnt(" #N ")" ::: "memory")
#define LGKM0 asm volatile("s_waitcnt lgkmcnt(0)" ::: "memory")

// ---------------------------------------------------------------------------
// gemm15: 256x256, BK=64, 512 thr (8 waves 2Mx4N), wave tile 128x64.
// sA: f16 [2 bufs][4 quarters][64][64] (64 KiB), reg-staged from fp32 X.
// sB: f16 [3 bufs][4 quarters][64][64] (96 KiB), DMA distance-2.
// Quarter layout (proven): slot u = r*8+bb holds row r block bb^(r&7).
// ---------------------------------------------------------------------------

#define ISSUE_B15(QI, KT1, BP)                                                 \
    __builtin_amdgcn_global_load_lds(                                          \
        (const AS1 void*)(Wl + rowOffB[QI] + (KT1) * 64 + swzc),               \
        (AS3 void*)(&sB[((BP) * 4 + (QI)) * 4096 + t * 8]), 16, 0, 0)

// A loads for tile KT1 into ar[8] (2 float4 per quarter-slot, 4 quarters).
#define A_LOADS15(KT1) do {                                                    \
    _Pragma("unroll")                                                          \
    for (int qi_ = 0; qi_ < 4; ++qi_) {                                        \
      const float* p_ = X + rowOffA[qi_] + (KT1) * 64 + swzc;                  \
      ar[2 * qi_]     = *reinterpret_cast<const float4*>(p_);                  \
      ar[2 * qi_ + 1] = *reinterpret_cast<const float4*>(p_ + 4);              \
    }                                                                          \
  } while (0)

// cvt + ds_write A tile into buffer AP1 (linear dest: content pre-permuted
// because the global source address carried the swizzle).
#define A_WRITE15(AP1) do {                                                    \
    _Pragma("unroll")                                                          \
    for (int qi_ = 0; qi_ < 4; ++qi_) {                                        \
      float4 v0_ = ar[2 * qi_], v1_ = ar[2 * qi_ + 1];                         \
      f16x8 h_ = {(f16)v0_.x, (f16)v0_.y, (f16)v0_.z, (f16)v0_.w,              \
                  (f16)v1_.x, (f16)v1_.y, (f16)v1_.z, (f16)v1_.w};             \
      *reinterpret_cast<f16x8*>(&sA[((AP1) * 4 + qi_) * 4096 + t * 8]) = h_;   \
    }                                                                          \
  } while (0)

#define DSREAD15(AP, BPr, S_) do {                                             \
    _Pragma("unroll")                                                          \
    for (int qq_ = 0; qq_ < 2; ++qq_) {                                        \
      int qa_ = ((AP) * 4 + wm * 2 + qq_) * 4096;                              \
      _Pragma("unroll")                                                        \
      for (int mf_ = 0; mf_ < 4; ++mf_) {                                      \
        int r_ = mf_ * 16 + lr;                                                \
        int blk_ = ((S_) * 4 + lk) ^ (lr & 7);                                 \
        afr[qq_][mf_] = *reinterpret_cast<const f16x8*>(&sA[qa_ + r_ * 64 + blk_ * 8]); \
      }                                                                        \
    }                                                                          \
    int qb_ = ((BPr) * 4 + wn) * 4096;                                         \
    _Pragma("unroll")                                                          \
    for (int nf_ = 0; nf_ < 4; ++nf_) {                                        \
      int r_ = nf_ * 16 + lr;                                                  \
      int blk_ = ((S_) * 4 + lk) ^ (lr & 7);                                   \
      bfr[nf_] = *reinterpret_cast<const f16x8*>(&sB[qb_ + r_ * 64 + blk_ * 8]); \
    }                                                                          \
  } while (0)

#define MFMA32_15 do {                                                         \
    __builtin_amdgcn_s_setprio(1);                                             \
    _Pragma("unroll")                                                          \
    for (int qq_ = 0; qq_ < 2; ++qq_)                                          \
      _Pragma("unroll")                                                        \
      for (int mf_ = 0; mf_ < 4; ++mf_)                                        \
        _Pragma("unroll")                                                      \
        for (int nf_ = 0; nf_ < 4; ++nf_)                                      \
          acc[qq_ * 4 + mf_][nf_] = __builtin_amdgcn_mfma_f32_16x16x32_f16(    \
              afr[qq_][mf_], bfr[nf_], acc[qq_ * 4 + mf_][nf_], 0, 0, 0);      \
    __builtin_amdgcn_s_setprio(0);                                             \
  } while (0)

// LD_A: stage A(KT+1); ISSB: DMA B(KT+2). Issue order (vmcnt FIFO): A-loads
// BEFORE B-DMA so the cvt wait drains only A (vmcnt(4)-style), keeping B.
#define KTILE15(AP, BPr, KT, LD_A, ISSB, VMN, GATE) do {                       \
    if (LD_A) { A_LOADS15((KT) + 1); }                                         \
    if (ISSB) { ISSUE_B15(0, (KT) + 2, ((KT) + 2) % 3);                        \
                ISSUE_B15(1, (KT) + 2, ((KT) + 2) % 3);                        \
                ISSUE_B15(2, (KT) + 2, ((KT) + 2) % 3);                        \
                ISSUE_B15(3, (KT) + 2, ((KT) + 2) % 3); }                      \
    SB0;                            /* pin issue-early */                      \
    DSREAD15(AP, BPr, 0);                                                      \
    MFMA32_15;                                                                 \
    DSREAD15(AP, BPr, 1);                                                      \
    MFMA32_15;                                                                 \
    if (LD_A) { A_WRITE15((AP) ^ 1); }   /* write-late (T14) */                \
    if (GATE) {                                                                \
      LGKM0;                        /* drain ds_writes + frag reads */         \
      VMW(VMN);                                                                \
      __builtin_amdgcn_s_barrier(); /* WAR(this) + RAW(next), r9 */            \
      SB0;                          /* hoist guard */                          \
    }                                                                          \
  } while (0)

__global__ void __launch_bounds__(512, 2) gemm15(const float* __restrict__ X,
                                                 const f16* __restrict__ Wl,
                                                 float* __restrict__ C) {
  extern __shared__ char lds[];
  f16* sA = (f16*)lds;                 // 2 x 4 x 4096 f16 = 64 KiB
  f16* sB = (f16*)(lds + 65536);       // 3 x 4 x 4096 f16 = 96 KiB

  int bidx = blockIdx.x;
  int q = gridDim.x >> 3;
  int wg = (bidx & 7) * q + (bidx >> 3);
  int mt = wg >> 2, nt = wg & 3;

  int t = threadIdx.x;
  int lane = t & 63;
  int w = t >> 6;
  int wm = w >> 2;           // M half (128 rows) -> A quarters 2wm, 2wm+1
  int wn = w & 3;            // N quarter (64 cols) == B row-quarter
  int lr = lane & 15;
  int lk = lane >> 4;

  int rS = t >> 3;
  int swzc = (((t & 7) ^ (rS & 7)) << 3);    // element units (f16 for B src,
                                             // f32 for A src -- both 8/blk)
  size_t rowOffA[4], rowOffB[4];
#pragma unroll
  for (int qi = 0; qi < 4; ++qi) {
    rowOffA[qi] = (size_t)(mt * 256 + qi * 64 + rS) * IN_F;
    rowOffB[qi] = (size_t)(nt * 256 + qi * 64 + rS) * IN_F;
  }

  float4 ar[8];
  f16x8 afr[2][4], bfr[4];
  f32x4 acc[8][4];
#pragma unroll
  for (int i = 0; i < 8; ++i)
#pragma unroll
    for (int j = 0; j < 4; ++j)
      acc[i][j] = (f32x4){0.f, 0.f, 0.f, 0.f};

  // prologue: A(0) loads; B(0)->B0, B(1)->B1 DMA; cvt+write A(0)->A0
  // (cvt wait drains A, keeps both B sets); lgkm(0); VMW(4) (drain B0,
  // keep B1); barrier (r9).
  A_LOADS15(0);
  ISSUE_B15(0, 0, 0); ISSUE_B15(1, 0, 0); ISSUE_B15(2, 0, 0); ISSUE_B15(3, 0, 0);
  ISSUE_B15(0, 1, 1); ISSUE_B15(1, 1, 1); ISSUE_B15(2, 1, 1); ISSUE_B15(3, 1, 1);
  SB0;
  A_WRITE15(0);
  LGKM0;
  VMW(4);
  __builtin_amdgcn_s_barrier();
  SB0;

  // KT: AP=KT&1, BPr=KT%3; LD_A: KT<=14; ISSB: KT<=13; VMN 4 (0 at KT=14).
  KTILE15(0, 0,  0, true,  true,  4, true);
  KTILE15(1, 1,  1, true,  true,  4, true);
  KTILE15(0, 2,  2, true,  true,  4, true);
  KTILE15(1, 0,  3, true,  true,  4, true);
  KTILE15(0, 1,  4, true,  true,  4, true);
  KTILE15(1, 2,  5, true,  true,  4, true);
  KTILE15(0, 0,  6, true,  true,  4, true);
  KTILE15(1, 1,  7, true,  true,  4, true);
  KTILE15(0, 2,  8, true,  true,  4, true);
  KTILE15(1, 0,  9, true,  true,  4, true);
  KTILE15(0, 1, 10, true,  true,  4, true);
  KTILE15(1, 2, 11, true,  true,  4, true);
  KTILE15(0, 0, 12, true,  true,  4, true);
  KTILE15(1, 1, 13, true,  true,  4, true);
  KTILE15(0, 2, 14, true,  false, 0, true);
  KTILE15(1, 0, 15, false, false, 0, false);

  // epilogue: D layout col = lane&15, row = (lane>>4)*4 + reg
  float* Cw = C + (size_t)(mt * 256 + wm * 128 + lk * 4) * OUT_F + nt * 256 + wn * 64 + lr;
#pragma unroll
  for (int m = 0; m < 8; ++m) {
    int rowo = (m >> 2) * 64 + (m & 3) * 16;
#pragma unroll
    for (int nf = 0; nf < 4; ++nf)
#pragma unroll
      for (int g = 0; g < 4; ++g)
        Cw[(size_t)(rowo + g) * OUT_F + nf * 16] = acc[m][nf][g];
  }
}

// ---------------------------------------------------------------------------
// gemm14 fallback (replay-proven r20/r21, ~105 us headline): fp32-A via DMA.
// ---------------------------------------------------------------------------

#define ISSUE_A14(QI, KT1, AP)                                                 \
    __builtin_amdgcn_global_load_lds(                                          \
        (const AS1 void*)(X + rowOffA[QI] + (KT1) * 32 + swzcA),               \
        (AS3 void*)(&sAf[((AP) * 4 + (QI)) * 2048 + t * 4]), 16, 0, 0)

#define ISSUE_B14(QI, KTB1, BP)                                                \
    __builtin_amdgcn_global_load_lds(                                          \
        (const AS1 void*)(Wl + rowOffB[QI] + (KTB1) * 64 + swzc),              \
        (AS3 void*)(&sB[((BP) * 4 + (QI)) * 4096 + t * 8]), 16, 0, 0)

#define DSREAD_A14(AP) do {                                                    \
    _Pragma("unroll")                                                          \
    for (int qq_ = 0; qq_ < 2; ++qq_) {                                        \
      int qa_ = ((AP) * 4 + wm * 2 + qq_) * 2048;                              \
      _Pragma("unroll")                                                        \
      for (int mf_ = 0; mf_ < 4; ++mf_) {                                      \
        int r_ = mf_ * 16 + lr;                                                \
        f32x4 a0_ = *reinterpret_cast<const f32x4*>(                           \
            &sAf[qa_ + r_ * 32 + (((2 * lk) ^ (r_ & 7)) << 2)]);               \
        f32x4 a1_ = *reinterpret_cast<const f32x4*>(                           \
            &sAf[qa_ + r_ * 32 + (((2 * lk + 1) ^ (r_ & 7)) << 2)]);           \
        afr[qq_][mf_] = (f16x8){(f16)a0_[0], (f16)a0_[1], (f16)a0_[2],         \
                                (f16)a0_[3], (f16)a1_[0], (f16)a1_[1],         \
                                (f16)a1_[2], (f16)a1_[3]};                     \
      }                                                                        \
    }                                                                          \
  } while (0)

#define DSREAD_B14(BP, S_) do {                                                \
    int qb_ = ((BP) * 4 + wn) * 4096;                                          \
    _Pragma("unroll")                                                          \
    for (int nf_ = 0; nf_ < 4; ++nf_) {                                        \
      int r_ = nf_ * 16 + lr;                                                  \
      int blk_ = ((S_) * 4 + lk) ^ (lr & 7);                                   \
      bfr[nf_] = *reinterpret_cast<const f16x8*>(&sB[qb_ + r_ * 64 + blk_ * 8]); \
    }                                                                          \
  } while (0)

#define KTILE14(AP, BP, S_, KT, ISSB, ISSA, VMN, GATE) do {                    \
    DSREAD_A14(AP);                                                            \
    DSREAD_B14(BP, S_);                                                        \
    if (ISSB) {                                                                \
      ISSUE_B14(0, ((KT) >> 1) + 1, (((KT) >> 1) + 1) & 1);                    \
      ISSUE_B14(1, ((KT) >> 1) + 1, (((KT) >> 1) + 1) & 1);                    \
      ISSUE_B14(2, ((KT) >> 1) + 1, (((KT) >> 1) + 1) & 1);                    \
      ISSUE_B14(3, ((KT) >> 1) + 1, (((KT) >> 1) + 1) & 1); }                  \
    MFMA32_15;                                                                 \
    if (ISSA) {                                                                \
      ISSUE_A14(0, (KT) + 2, ((KT) + 2) % 3);                                  \
      ISSUE_A14(1, (KT) + 2, ((KT) + 2) % 3);                                  \
      ISSUE_A14(2, (KT) + 2, ((KT) + 2) % 3);                                  \
      ISSUE_A14(3, (KT) + 2, ((KT) + 2) % 3); }                                \
    if (GATE) {                                                                \
      VMW(VMN);                                                                \
      __builtin_amdgcn_s_barrier();                                            \
      SB0;                                                                     \
    }                                                                          \
  } while (0)

__global__ void __launch_bounds__(512, 2) gemm14(const float* __restrict__ X,
                                                 const f16* __restrict__ Wl,
                                                 float* __restrict__ C) {
  extern __shared__ char lds[];
  float* sAf = (float*)lds;
  f16* sB = (f16*)(lds + 98304);

  int bidx = blockIdx.x;
  int q = gridDim.x >> 3;
  int wg = (bidx & 7) * q + (bidx >> 3);
  int mt = wg >> 2, nt = wg & 3;

  int t = threadIdx.x;
  int lane = t & 63;
  int w = t >> 6;
  int wm = w >> 2;
  int wn = w & 3;
  int lr = lane & 15;
  int lk = lane >> 4;

  int rS = t >> 3;
  int swzc = (((t & 7) ^ (rS & 7)) << 3);
  int swzcA = (((t & 7) ^ (rS & 7)) << 2);
  size_t rowOffA[4], rowOffB[4];
#pragma unroll
  for (int qi = 0; qi < 4; ++qi) {
    rowOffA[qi] = (size_t)(mt * 256 + qi * 64 + rS) * IN_F;
    rowOffB[qi] = (size_t)(nt * 256 + qi * 64 + rS) * IN_F;
  }

  f16x8 afr[2][4], bfr[4];
  f32x4 acc[8][4];
#pragma unroll
  for (int i = 0; i < 8; ++i)
#pragma unroll
    for (int j = 0; j < 4; ++j)
      acc[i][j] = (f32x4){0.f, 0.f, 0.f, 0.f};

  ISSUE_A14(0, 0, 0); ISSUE_A14(1, 0, 0); ISSUE_A14(2, 0, 0); ISSUE_A14(3, 0, 0);
  ISSUE_B14(0, 0, 0); ISSUE_B14(1, 0, 0); ISSUE_B14(2, 0, 0); ISSUE_B14(3, 0, 0);
  ISSUE_A14(0, 1, 1); ISSUE_A14(1, 1, 1); ISSUE_A14(2, 1, 1); ISSUE_A14(3, 1, 1);
  VMW(4);
  __builtin_amdgcn_s_barrier();
  SB0;

  KTILE14(0, 0, 0,  0, true,  true,  8, true);
  KTILE14(1, 0, 1,  1, false, true,  4, true);
  KTILE14(2, 1, 0,  2, true,  true,  8, true);
  KTILE14(0, 1, 1,  3, false, true,  4, true);
  KTILE14(1, 0, 0,  4, true,  true,  8, true);
  KTILE14(2, 0, 1,  5, false, true,  4, true);
  KTILE14(0, 1, 0,  6, true,  true,  8, true);
  KTILE14(1, 1, 1,  7, false, true,  4, true);
  KTILE14(2, 0, 0,  8, true,  true,  8, true);
  KTILE14(0, 0, 1,  9, false, true,  4, true);
  KTILE14(1, 1, 0, 10, true,  true,  8, true);
  KTILE14(2, 1, 1, 11, false, true,  4, true);
  KTILE14(0, 0, 0, 12, true,  true,  8, true);
  KTILE14(1, 0, 1, 13, false, true,  4, true);
  KTILE14(2, 1, 0, 14, true,  true,  8, true);
  KTILE14(0, 1, 1, 15, false, true,  4, true);
  KTILE14(1, 0, 0, 16, true,  true,  8, true);
  KTILE14(2, 0, 1, 17, false, true,  4, true);
  KTILE14(0, 1, 0, 18, true,  true,  8, true);
  KTILE14(1, 1, 1, 19, false, true,  4, true);
  KTILE14(2, 0, 0, 20, true,  true,  8, true);
  KTILE14(0, 0, 1, 21, false, true,  4, true);
  KTILE14(1, 1, 0, 22, true,  true,  8, true);
  KTILE14(2, 1, 1, 23, false, true,  4, true);
  KTILE14(0, 0, 0, 24, true,  true,  8, true);
  KTILE14(1, 0, 1, 25, false, true,  4, true);
  KTILE14(2, 1, 0, 26, true,  true,  8, true);
  KTILE14(0, 1, 1, 27, false, true,  4, true);
  KTILE14(1, 0, 0, 28, true,  true,  8, true);
  KTILE14(2, 0, 1, 29, false, true,  4, true);
  KTILE14(0, 1, 0, 30, false, false, 0, true);
  KTILE14(1, 1, 1, 31, false, false, 0, false);

  float* Cw = C + (size_t)(mt * 256 + wm * 128 + lk * 4) * OUT_F + nt * 256 + wn * 64 + lr;
#pragma unroll
  for (int m = 0; m < 8; ++m) {
    int rowo = (m >> 2) * 64 + (m & 3) * 16;
#pragma unroll
    for (int nf = 0; nf < 4; ++nf)
#pragma unroll
      for (int g = 0; g < 4; ++g)
        Cw[(size_t)(rowo + g) * OUT_F + nf * 16] = acc[m][nf][g];
  }
}

extern "C" void kernel_launch(void* const* d_in, const int* in_sizes, int n_in,
                              void* d_out, int out_size, void* d_ws, size_t ws_size,
                              hipStream_t stream) {
  const float* X = (const float*)d_in[0];
  const void* base = d_in[1];
  const void* vals = d_in[2];
  const int* idx = (const int*)d_in[3];
  const float* alpha = (const float*)d_in[4];
  float* out = (float*)d_out;
  f16* Wl = (f16*)d_ws;                                   // linear W_eff

  int M = in_sizes[0] / IN_F;              // 32768

  prep_base<<<dim3(512), dim3(256), 0, stream>>>(base, Wl);
  prep_scatter<<<dim3(64), dim3(256), 0, stream>>>(base, vals, idx, alpha, Wl);

  hipError_t e = hipFuncSetAttribute(reinterpret_cast<const void*>(&gemm15),
                                     hipFuncAttributeMaxDynamicSharedMemorySize, 163840);
  if (e == hipSuccess) {
    gemm15<<<dim3((M / 256) * 4), dim3(512), 163840, stream>>>(X, Wl, out);
  } else {
    (void)hipFuncSetAttribute(reinterpret_cast<const void*>(&gemm14),
                              hipFuncAttributeMaxDynamicSharedMemorySize, 163840);
    gemm14<<<dim3((M / 256) * 4), dim3(512), 163840, stream>>>(X, Wl, out);
  }
}

// Round 23
// 104.632 us; speedup vs baseline: 1.1235x; 1.1235x over previous
//
#include <hip/hip_runtime.h>

#define IN_F 1024
#define OUT_F 1024
#define NNZ 16384

typedef _Float16 f16;
typedef _Float16 f16x8 __attribute__((ext_vector_type(8)));
typedef float f32x4 __attribute__((ext_vector_type(4)));
typedef unsigned short ushort8 __attribute__((ext_vector_type(8)));

#define AS1 __attribute__((address_space(1)))
#define AS3 __attribute__((address_space(3)))

// ---------------------------------------------------------------------------
// FINAL (r23 = r20/r21 verbatim, session best: 105 us headline).
// Pipeline: prep_base (linear W cvt) -> prep_scatter -> gemm14.
// gemm14 DMAs fp32 X straight to LDS (global_load_lds, pre-swizzled source)
// and converts at fragment read (compiler-fused cvt). A: BK=32 fp32 quarters
// [64][32], triple-buffered (96 KiB). B: f16 K=64 tiles, double-buffered
// (64 KiB). Counted vmcnt gates (VMW(8)/VMW(4), 0 only at tile 30).
// Session ledger: 7 schedules, 2 MFMA shapes, 3 A-formats, B-placement,
// occupancy all measured. gemm15 (reg-staged cvt, r22) regressed ->
// reverted per pre-committed gate. Further gains need inline-asm-class
// scheduling (hipBLASLt/Tensile territory), not plain-HIP restructuring.
// SYNC INVARIANT (r9): VMW(n) -> s_barrier before cross-wave LDS read.
// Workspace: Wl = LINEAR W_eff (2 MiB) @0; Xs @2MiB+4096 (fallback only).
// ---------------------------------------------------------------------------

__device__ __forceinline__ int compute_mode(const unsigned short* __restrict__ w,
                                            float* smax, int* semax) {
  int t = threadIdx.x;
  const float* wf = (const float*)w;
  float m32 = fmaxf(fabsf(wf[t]), fabsf(wf[t + 256]));
  int e8 = 0;
#pragma unroll
  for (int j = 0; j < 8; ++j) {
    unsigned short u = w[t * 8 + j];
    int e = (u >> 7) & 0xFF;
    e8 = e > e8 ? e : e8;
  }
  smax[t] = m32; semax[t] = e8;
  __syncthreads();
  for (int s = 128; s > 0; s >>= 1) {
    if (t < s) {
      smax[t] = fmaxf(smax[t], smax[t + s]);
      semax[t] = semax[t] > semax[t + s] ? semax[t] : semax[t + s];
    }
    __syncthreads();
  }
  int m;
  if (!(smax[0] > 1e-6f)) m = 2;        // native f16
  else if (semax[0] >= 140) m = 0;      // f32-upcast
  else m = 1;                           // bf16
  return m;
}

__device__ __forceinline__ float load_w(const void* base, size_t i, int mode) {
  if (mode == 0) return ((const float*)base)[i];
  if (mode == 1) {
    unsigned int u = (unsigned int)((const unsigned short*)base)[i] << 16;
    return __uint_as_float(u);
  }
  return (float)((const f16*)base)[i];
}

__global__ void prep_base(const void* __restrict__ base, f16* __restrict__ Wl) {
  __shared__ float smax[256];
  __shared__ int semax[256];
  int mode = compute_mode((const unsigned short*)base, smax, semax);
  int id = blockIdx.x * 256 + threadIdx.x;
  size_t off = (size_t)id * 8;
  f16x8 h;
  if (mode == 0) {
    const float* b = (const float*)base + off;
    float4 v0 = *reinterpret_cast<const float4*>(b);
    float4 v1 = *reinterpret_cast<const float4*>(b + 4);
    h = (f16x8){(f16)v0.x, (f16)v0.y, (f16)v0.z, (f16)v0.w,
                (f16)v1.x, (f16)v1.y, (f16)v1.z, (f16)v1.w};
  } else if (mode == 1) {
    ushort8 uv = *reinterpret_cast<const ushort8*>((const unsigned short*)base + off);
#pragma unroll
    for (int j = 0; j < 8; ++j)
      h[j] = (f16)__uint_as_float((unsigned int)uv[j] << 16);
  } else {
    h = *reinterpret_cast<const f16x8*>((const f16*)base + off);
  }
  *reinterpret_cast<f16x8*>(Wl + off) = h;
}

__global__ void prep_scatter(const void* __restrict__ base,
                             const void* __restrict__ vals,
                             const int* __restrict__ idx,
                             const float* __restrict__ alpha,
                             f16* __restrict__ Wl) {
  __shared__ float smax[256];
  __shared__ int semax[256];
  int mode = compute_mode((const unsigned short*)base, smax, semax);
  int i = blockIdx.x * 256 + threadIdx.x;
  if (i >= NNZ) return;
  int id = idx[i];
  float v = load_w(base, id, mode) + alpha[0] * load_w(vals, i, mode);
  Wl[id] = (f16)v;
}

// conv_x (fallback path only): linear cvt copy.
__global__ void __launch_bounds__(256) conv_x(const float* __restrict__ X,
                                              f16* __restrict__ Xs, int total) {
  int stride = gridDim.x * 256;
  for (int id = blockIdx.x * 256 + threadIdx.x; id < total; id += stride) {
    size_t off = (size_t)id * 8;
    const float* p = X + off;
    float4 v0 = *reinterpret_cast<const float4*>(p);
    float4 v1 = *reinterpret_cast<const float4*>(p + 4);
    f16x8 h = {(f16)v0.x, (f16)v0.y, (f16)v0.z, (f16)v0.w,
               (f16)v1.x, (f16)v1.y, (f16)v1.z, (f16)v1.w};
    *reinterpret_cast<f16x8*>(Xs + off) = h;
  }
}

#define SB0 __builtin_amdgcn_sched_barrier(0)
#define VMW(N) asm volatile("s_waitcnt vmcnt(" #N ")" ::: "memory")

// ---------------------------------------------------------------------------
// gemm14: 256x256, 512 thr (8 waves 2Mx4N), wave tile 128x64.
// A: fp32, BK=32, 32 K-tiles, triple-buffered [3][4 quarters][64][32]f32.
// B: f16, K=64 tiles (ktB = KT>>1), double-buffered [2][4 quarters][64][64].
// Tile KT: {ds_read A(+cvt) & B(S=KT&1); even: issue B(ktB+1); 32 MFMA;
//           KT<=29: issue A(KT+2); gate: VMW(8 even / 4 odd) -> s_barrier
//           -> SB0}. VMW(0) only at KT=30; no gate after KT=31.
// ---------------------------------------------------------------------------

#define ISSUE_A14(QI, KT1, AP)                                                 \
    __builtin_amdgcn_global_load_lds(                                          \
        (const AS1 void*)(X + rowOffA[QI] + (KT1) * 32 + swzcA),               \
        (AS3 void*)(&sAf[((AP) * 4 + (QI)) * 2048 + t * 4]), 16, 0, 0)

#define ISSUE_B14(QI, KTB1, BP)                                                \
    __builtin_amdgcn_global_load_lds(                                          \
        (const AS1 void*)(Wl + rowOffB[QI] + (KTB1) * 64 + swzc),              \
        (AS3 void*)(&sB[((BP) * 4 + (QI)) * 4096 + t * 8]), 16, 0, 0)

#define DSREAD_A14(AP) do {                                                    \
    _Pragma("unroll")                                                          \
    for (int qq_ = 0; qq_ < 2; ++qq_) {                                        \
      int qa_ = ((AP) * 4 + wm * 2 + qq_) * 2048;                              \
      _Pragma("unroll")                                                        \
      for (int mf_ = 0; mf_ < 4; ++mf_) {                                      \
        int r_ = mf_ * 16 + lr;                                                \
        f32x4 a0_ = *reinterpret_cast<const f32x4*>(                           \
            &sAf[qa_ + r_ * 32 + (((2 * lk) ^ (r_ & 7)) << 2)]);               \
        f32x4 a1_ = *reinterpret_cast<const f32x4*>(                           \
            &sAf[qa_ + r_ * 32 + (((2 * lk + 1) ^ (r_ & 7)) << 2)]);           \
        afr[qq_][mf_] = (f16x8){(f16)a0_[0], (f16)a0_[1], (f16)a0_[2],         \
                                (f16)a0_[3], (f16)a1_[0], (f16)a1_[1],         \
                                (f16)a1_[2], (f16)a1_[3]};                     \
      }                                                                        \
    }                                                                          \
  } while (0)

#define DSREAD_B14(BP, S_) do {                                                \
    int qb_ = ((BP) * 4 + wn) * 4096;                                          \
    _Pragma("unroll")                                                          \
    for (int nf_ = 0; nf_ < 4; ++nf_) {                                        \
      int r_ = nf_ * 16 + lr;                                                  \
      int blk_ = ((S_) * 4 + lk) ^ (lr & 7);                                   \
      bfr[nf_] = *reinterpret_cast<const f16x8*>(&sB[qb_ + r_ * 64 + blk_ * 8]); \
    }                                                                          \
  } while (0)

#define MFMA32_14 do {                                                         \
    __builtin_amdgcn_s_setprio(1);                                             \
    _Pragma("unroll")                                                          \
    for (int qq_ = 0; qq_ < 2; ++qq_)                                          \
      _Pragma("unroll")                                                        \
      for (int mf_ = 0; mf_ < 4; ++mf_)                                        \
        _Pragma("unroll")                                                      \
        for (int nf_ = 0; nf_ < 4; ++nf_)                                      \
          acc[qq_ * 4 + mf_][nf_] = __builtin_amdgcn_mfma_f32_16x16x32_f16(    \
              afr[qq_][mf_], bfr[nf_], acc[qq_ * 4 + mf_][nf_], 0, 0, 0);      \
    __builtin_amdgcn_s_setprio(0);                                             \
  } while (0)

#define KTILE14(AP, BP, S_, KT, ISSB, ISSA, VMN, GATE) do {                    \
    DSREAD_A14(AP);                                                            \
    DSREAD_B14(BP, S_);                                                        \
    if (ISSB) {                                                                \
      ISSUE_B14(0, ((KT) >> 1) + 1, (((KT) >> 1) + 1) & 1);                    \
      ISSUE_B14(1, ((KT) >> 1) + 1, (((KT) >> 1) + 1) & 1);                    \
      ISSUE_B14(2, ((KT) >> 1) + 1, (((KT) >> 1) + 1) & 1);                    \
      ISSUE_B14(3, ((KT) >> 1) + 1, (((KT) >> 1) + 1) & 1); }                  \
    MFMA32_14;                                                                 \
    if (ISSA) {                                                                \
      ISSUE_A14(0, (KT) + 2, ((KT) + 2) % 3);                                  \
      ISSUE_A14(1, (KT) + 2, ((KT) + 2) % 3);                                  \
      ISSUE_A14(2, (KT) + 2, ((KT) + 2) % 3);                                  \
      ISSUE_A14(3, (KT) + 2, ((KT) + 2) % 3); }                                \
    if (GATE) {                                                                \
      VMW(VMN);                                                                \
      __builtin_amdgcn_s_barrier();  /* WAR(this) + RAW(next), r9 */           \
      SB0;                           /* hoist guard */                         \
    }                                                                          \
  } while (0)

__global__ void __launch_bounds__(512, 2) gemm14(const float* __restrict__ X,
                                                 const f16* __restrict__ Wl,
                                                 float* __restrict__ C) {
  extern __shared__ char lds[];
  float* sAf = (float*)lds;                    // 3 x 4 x 2048 f32 = 96 KiB
  f16* sB = (f16*)(lds + 98304);               // 2 x 4 x 4096 f16 = 64 KiB

  int bidx = blockIdx.x;
  int q = gridDim.x >> 3;
  int wg = (bidx & 7) * q + (bidx >> 3);
  int mt = wg >> 2, nt = wg & 3;

  int t = threadIdx.x;
  int lane = t & 63;
  int w = t >> 6;
  int wm = w >> 2;           // M half (128 rows) -> A quarters 2wm, 2wm+1
  int wn = w & 3;            // N quarter (64 cols) == B row-quarter
  int lr = lane & 15;
  int lk = lane >> 4;

  int rS = t >> 3;
  int swzc = (((t & 7) ^ (rS & 7)) << 3);      // f16 units (B)
  int swzcA = (((t & 7) ^ (rS & 7)) << 2);     // f32 units (A)
  size_t rowOffA[4], rowOffB[4];
#pragma unroll
  for (int qi = 0; qi < 4; ++qi) {
    rowOffA[qi] = (size_t)(mt * 256 + qi * 64 + rS) * IN_F;
    rowOffB[qi] = (size_t)(nt * 256 + qi * 64 + rS) * IN_F;
  }

  f16x8 afr[2][4], bfr[4];
  f32x4 acc[8][4];
#pragma unroll
  for (int i = 0; i < 8; ++i)
#pragma unroll
    for (int j = 0; j < 4; ++j)
      acc[i][j] = (f32x4){0.f, 0.f, 0.f, 0.f};

  // prologue: A(0)->buf0, B(0)->bufB0, A(1)->buf1; VMW(4) drains A0+B0,
  // keeps A(1) in flight; barrier (r9).
  ISSUE_A14(0, 0, 0); ISSUE_A14(1, 0, 0); ISSUE_A14(2, 0, 0); ISSUE_A14(3, 0, 0);
  ISSUE_B14(0, 0, 0); ISSUE_B14(1, 0, 0); ISSUE_B14(2, 0, 0); ISSUE_B14(3, 0, 0);
  ISSUE_A14(0, 1, 1); ISSUE_A14(1, 1, 1); ISSUE_A14(2, 1, 1); ISSUE_A14(3, 1, 1);
  VMW(4);
  __builtin_amdgcn_s_barrier();
  SB0;

  // KT: AP=KT%3, BP=(KT>>1)&1, S=KT&1; ISSB: even KT<=28; ISSA: KT<=29;
  // VMN: even 8 / odd 4; KT=30: VMW(0); KT=31: no gate.
  KTILE14(0, 0, 0,  0, true,  true,  8, true);
  KTILE14(1, 0, 1,  1, false, true,  4, true);
  KTILE14(2, 1, 0,  2, true,  true,  8, true);
  KTILE14(0, 1, 1,  3, false, true,  4, true);
  KTILE14(1, 0, 0,  4, true,  true,  8, true);
  KTILE14(2, 0, 1,  5, false, true,  4, true);
  KTILE14(0, 1, 0,  6, true,  true,  8, true);
  KTILE14(1, 1, 1,  7, false, true,  4, true);
  KTILE14(2, 0, 0,  8, true,  true,  8, true);
  KTILE14(0, 0, 1,  9, false, true,  4, true);
  KTILE14(1, 1, 0, 10, true,  true,  8, true);
  KTILE14(2, 1, 1, 11, false, true,  4, true);
  KTILE14(0, 0, 0, 12, true,  true,  8, true);
  KTILE14(1, 0, 1, 13, false, true,  4, true);
  KTILE14(2, 1, 0, 14, true,  true,  8, true);
  KTILE14(0, 1, 1, 15, false, true,  4, true);
  KTILE14(1, 0, 0, 16, true,  true,  8, true);
  KTILE14(2, 0, 1, 17, false, true,  4, true);
  KTILE14(0, 1, 0, 18, true,  true,  8, true);
  KTILE14(1, 1, 1, 19, false, true,  4, true);
  KTILE14(2, 0, 0, 20, true,  true,  8, true);
  KTILE14(0, 0, 1, 21, false, true,  4, true);
  KTILE14(1, 1, 0, 22, true,  true,  8, true);
  KTILE14(2, 1, 1, 23, false, true,  4, true);
  KTILE14(0, 0, 0, 24, true,  true,  8, true);
  KTILE14(1, 0, 1, 25, false, true,  4, true);
  KTILE14(2, 1, 0, 26, true,  true,  8, true);
  KTILE14(0, 1, 1, 27, false, true,  4, true);
  KTILE14(1, 0, 0, 28, true,  true,  8, true);
  KTILE14(2, 0, 1, 29, false, true,  4, true);
  KTILE14(0, 1, 0, 30, false, false, 0, true);
  KTILE14(1, 1, 1, 31, false, false, 0, false);

  // epilogue: D layout col = lane&15, row = (lane>>4)*4 + reg
  float* Cw = C + (size_t)(mt * 256 + wm * 128 + lk * 4) * OUT_F + nt * 256 + wn * 64 + lr;
#pragma unroll
  for (int m = 0; m < 8; ++m) {
    int rowo = (m >> 2) * 64 + (m & 3) * 16;
#pragma unroll
    for (int nf = 0; nf < 4; ++nf)
#pragma unroll
      for (int g = 0; g < 4; ++g)
        Cw[(size_t)(rowo + g) * OUT_F + nf * 16] = acc[m][nf][g];
  }
}

// ---------------------------------------------------------------------------
// gemm12 fallback (replay-proven r15-r18, ~71 us): f16 A via Xs + conv_x.
// ---------------------------------------------------------------------------

#define ISSUE_QA11(QI, KT1, AP)                                                \
    __builtin_amdgcn_global_load_lds(                                          \
        (const AS1 void*)(Xs + rowOffA[QI] + (KT1) * 64 + swzc),               \
        (AS3 void*)(&sA[((AP) * 4 + (QI)) * 4096 + t * 8]), 16, 0, 0)

#define ISSUE_QB11(QI, KT1, BP)                                                \
    __builtin_amdgcn_global_load_lds(                                          \
        (const AS1 void*)(Wl + rowOffB[QI] + (KT1) * 64 + swzc),               \
        (AS3 void*)(&sB[((BP) * 4 + (QI)) * 4096 + t * 8]), 16, 0, 0)

#define DSREAD11(AP, BP, S_) do {                                              \
    _Pragma("unroll")                                                          \
    for (int qq_ = 0; qq_ < 2; ++qq_) {                                        \
      int qa_ = ((AP) * 4 + wm * 2 + qq_) * 4096;                              \
      _Pragma("unroll")                                                        \
      for (int mf_ = 0; mf_ < 4; ++mf_) {                                      \
        int r_ = mf_ * 16 + lr;                                                \
        int blk_ = ((S_) * 4 + lk) ^ (lr & 7);                                 \
        afr[qq_][mf_] = *reinterpret_cast<const f16x8*>(&sA[qa_ + r_ * 64 + blk_ * 8]); \
      }                                                                        \
    }                                                                          \
    int qb_ = ((BP) * 4 + wn) * 4096;                                          \
    _Pragma("unroll")                                                          \
    for (int nf_ = 0; nf_ < 4; ++nf_) {                                        \
      int r_ = nf_ * 16 + lr;                                                  \
      int blk_ = ((S_) * 4 + lk) ^ (lr & 7);                                   \
      bfr[nf_] = *reinterpret_cast<const f16x8*>(&sB[qb_ + r_ * 64 + blk_ * 8]); \
    }                                                                          \
  } while (0)

#define KTILE12(AP, BP, KT, ISSB, ISSA, VMN, LASTBAR) do {                     \
    DSREAD11(AP, BP, 0);                                                       \
    if (ISSB) {                                                                \
      ISSUE_QB11(0, (KT) + 1, ((KT) + 1) & 1); ISSUE_QB11(1, (KT) + 1, ((KT) + 1) & 1); \
      ISSUE_QB11(2, (KT) + 1, ((KT) + 1) & 1); ISSUE_QB11(3, (KT) + 1, ((KT) + 1) & 1); } \
    MFMA32_14;                                                                 \
    DSREAD11(AP, BP, 1);                                                       \
    if (ISSA) {                                                                \
      ISSUE_QA11(0, (KT) + 2, ((KT) + 2) % 3); ISSUE_QA11(1, (KT) + 2, ((KT) + 2) % 3); \
      ISSUE_QA11(2, (KT) + 2, ((KT) + 2) % 3); ISSUE_QA11(3, (KT) + 2, ((KT) + 2) % 3); } \
    MFMA32_14;                                                                 \
    if (LASTBAR) {                                                             \
      VMW(VMN);                                                                \
      __builtin_amdgcn_s_barrier();                                            \
      SB0;                                                                     \
    }                                                                          \
  } while (0)

__global__ void __launch_bounds__(512, 2) gemm12(const f16* __restrict__ Xs,
                                                 const f16* __restrict__ Wl,
                                                 float* __restrict__ C) {
  extern __shared__ char lds[];
  f16* sA = (f16*)lds;
  f16* sB = (f16*)(lds + 98304);

  int bidx = blockIdx.x;
  int q = gridDim.x >> 3;
  int wg = (bidx & 7) * q + (bidx >> 3);
  int mt = wg >> 2, nt = wg & 3;

  int t = threadIdx.x;
  int lane = t & 63;
  int w = t >> 6;
  int wm = w >> 2;
  int wn = w & 3;
  int lr = lane & 15;
  int lk = lane >> 4;

  int rS = t >> 3;
  int swzc = (((t & 7) ^ (rS & 7)) << 3);
  size_t rowOffA[4], rowOffB[4];
#pragma unroll
  for (int qi = 0; qi < 4; ++qi) {
    rowOffA[qi] = (size_t)(mt * 256 + qi * 64 + rS) * IN_F;
    rowOffB[qi] = (size_t)(nt * 256 + qi * 64 + rS) * IN_F;
  }

  f16x8 afr[2][4], bfr[4];
  f32x4 acc[8][4];
#pragma unroll
  for (int i = 0; i < 8; ++i)
#pragma unroll
    for (int j = 0; j < 4; ++j)
      acc[i][j] = (f32x4){0.f, 0.f, 0.f, 0.f};

  ISSUE_QA11(0, 0, 0); ISSUE_QA11(1, 0, 0); ISSUE_QA11(2, 0, 0); ISSUE_QA11(3, 0, 0);
  ISSUE_QB11(0, 0, 0); ISSUE_QB11(1, 0, 0); ISSUE_QB11(2, 0, 0); ISSUE_QB11(3, 0, 0);
  ISSUE_QA11(0, 1, 1); ISSUE_QA11(1, 1, 1); ISSUE_QA11(2, 1, 1); ISSUE_QA11(3, 1, 1);
  VMW(4);
  __builtin_amdgcn_s_barrier();
  SB0;

  KTILE12(0, 0,  0, true,  true,  4, true);
  KTILE12(1, 1,  1, true,  true,  4, true);
  KTILE12(2, 0,  2, true,  true,  4, true);
  KTILE12(0, 1,  3, true,  true,  4, true);
  KTILE12(1, 0,  4, true,  true,  4, true);
  KTILE12(2, 1,  5, true,  true,  4, true);
  KTILE12(0, 0,  6, true,  true,  4, true);
  KTILE12(1, 1,  7, true,  true,  4, true);
  KTILE12(2, 0,  8, true,  true,  4, true);
  KTILE12(0, 1,  9, true,  true,  4, true);
  KTILE12(1, 0, 10, true,  true,  4, true);
  KTILE12(2, 1, 11, true,  true,  4, true);
  KTILE12(0, 0, 12, true,  true,  4, true);
  KTILE12(1, 1, 13, true,  true,  4, true);
  KTILE12(2, 0, 14, true,  false, 0, true);
  KTILE12(0, 1, 15, false, false, 0, false);

  float* Cw = C + (size_t)(mt * 256 + wm * 128 + lk * 4) * OUT_F + nt * 256 + wn * 64 + lr;
#pragma unroll
  for (int m = 0; m < 8; ++m) {
    int rowo = (m >> 2) * 64 + (m & 3) * 16;
#pragma unroll
    for (int nf = 0; nf < 4; ++nf)
#pragma unroll
      for (int g = 0; g < 4; ++g)
        Cw[(size_t)(rowo + g) * OUT_F + nf * 16] = acc[m][nf][g];
  }
}

extern "C" void kernel_launch(void* const* d_in, const int* in_sizes, int n_in,
                              void* d_out, int out_size, void* d_ws, size_t ws_size,
                              hipStream_t stream) {
  const float* X = (const float*)d_in[0];
  const void* base = d_in[1];
  const void* vals = d_in[2];
  const int* idx = (const int*)d_in[3];
  const float* alpha = (const float*)d_in[4];
  float* out = (float*)d_out;
  f16* Wl = (f16*)d_ws;                                   // linear W_eff
  f16* Xs = (f16*)((char*)d_ws + 2 * 1024 * 1024 + 4096); // fallback only

  int M = in_sizes[0] / IN_F;              // 32768
  int total = (M * IN_F) / 8;

  prep_base<<<dim3(512), dim3(256), 0, stream>>>(base, Wl);
  prep_scatter<<<dim3(64), dim3(256), 0, stream>>>(base, vals, idx, alpha, Wl);

  hipError_t e = hipFuncSetAttribute(reinterpret_cast<const void*>(&gemm14),
                                     hipFuncAttributeMaxDynamicSharedMemorySize, 163840);
  if (e == hipSuccess) {
    gemm14<<<dim3((M / 256) * 4), dim3(512), 163840, stream>>>(X, Wl, out);
  } else {
    (void)hipFuncSetAttribute(reinterpret_cast<const void*>(&gemm12),
                              hipFuncAttributeMaxDynamicSharedMemorySize, 163840);
    conv_x<<<dim3(2048), dim3(256), 0, stream>>>(X, Xs, total);
    gemm12<<<dim3((M / 256) * 4), dim3(512), 163840, stream>>>(Xs, Wl, out);
  }
}

// Round 24
// 100.287 us; speedup vs baseline: 1.1722x; 1.0433x over previous
//
#include <hip/hip_runtime.h>

#define IN_F 1024
#define OUT_F 1024
#define NNZ 16384

typedef _Float16 f16;
typedef _Float16 f16x8 __attribute__((ext_vector_type(8)));
typedef float f32x4 __attribute__((ext_vector_type(4)));
typedef unsigned short ushort8 __attribute__((ext_vector_type(8)));

#define AS1 __attribute__((address_space(1)))
#define AS3 __attribute__((address_space(3)))

// ---------------------------------------------------------------------------
// r24: gemm14b = gemm14 with 4Mx2N wave tiling (wave tile 64x128).
// Rationale: operands have asymmetric byte-widths (A fp32, B f16); LDS read
// amplification should be shifted off the wide operand. 2Mx4N: A quarters
// read by 4 waves (16 ds_read/wave/tile) + B 4 = 20. 4Mx2N: A by 2 waves
// (8 reads) + B 8 = 16 -> -20% LDS service, the dominant measured term.
// Everything else r23-verbatim: fp32-A DMA (BK=32, triple buf), f16-B DMA
// (K=64, double buf), counted vmcnt gates, proven swizzled layouts.
// SYNC INVARIANT (r9): VMW(n) -> s_barrier before cross-wave LDS read.
// Workspace: Wl = LINEAR W_eff (2 MiB) @0; Xs @2MiB+4096 (fallback only).
// ---------------------------------------------------------------------------

__device__ __forceinline__ int compute_mode(const unsigned short* __restrict__ w,
                                            float* smax, int* semax) {
  int t = threadIdx.x;
  const float* wf = (const float*)w;
  float m32 = fmaxf(fabsf(wf[t]), fabsf(wf[t + 256]));
  int e8 = 0;
#pragma unroll
  for (int j = 0; j < 8; ++j) {
    unsigned short u = w[t * 8 + j];
    int e = (u >> 7) & 0xFF;
    e8 = e > e8 ? e : e8;
  }
  smax[t] = m32; semax[t] = e8;
  __syncthreads();
  for (int s = 128; s > 0; s >>= 1) {
    if (t < s) {
      smax[t] = fmaxf(smax[t], smax[t + s]);
      semax[t] = semax[t] > semax[t + s] ? semax[t] : semax[t + s];
    }
    __syncthreads();
  }
  int m;
  if (!(smax[0] > 1e-6f)) m = 2;        // native f16
  else if (semax[0] >= 140) m = 0;      // f32-upcast
  else m = 1;                           // bf16
  return m;
}

__device__ __forceinline__ float load_w(const void* base, size_t i, int mode) {
  if (mode == 0) return ((const float*)base)[i];
  if (mode == 1) {
    unsigned int u = (unsigned int)((const unsigned short*)base)[i] << 16;
    return __uint_as_float(u);
  }
  return (float)((const f16*)base)[i];
}

__global__ void prep_base(const void* __restrict__ base, f16* __restrict__ Wl) {
  __shared__ float smax[256];
  __shared__ int semax[256];
  int mode = compute_mode((const unsigned short*)base, smax, semax);
  int id = blockIdx.x * 256 + threadIdx.x;
  size_t off = (size_t)id * 8;
  f16x8 h;
  if (mode == 0) {
    const float* b = (const float*)base + off;
    float4 v0 = *reinterpret_cast<const float4*>(b);
    float4 v1 = *reinterpret_cast<const float4*>(b + 4);
    h = (f16x8){(f16)v0.x, (f16)v0.y, (f16)v0.z, (f16)v0.w,
                (f16)v1.x, (f16)v1.y, (f16)v1.z, (f16)v1.w};
  } else if (mode == 1) {
    ushort8 uv = *reinterpret_cast<const ushort8*>((const unsigned short*)base + off);
#pragma unroll
    for (int j = 0; j < 8; ++j)
      h[j] = (f16)__uint_as_float((unsigned int)uv[j] << 16);
  } else {
    h = *reinterpret_cast<const f16x8*>((const f16*)base + off);
  }
  *reinterpret_cast<f16x8*>(Wl + off) = h;
}

__global__ void prep_scatter(const void* __restrict__ base,
                             const void* __restrict__ vals,
                             const int* __restrict__ idx,
                             const float* __restrict__ alpha,
                             f16* __restrict__ Wl) {
  __shared__ float smax[256];
  __shared__ int semax[256];
  int mode = compute_mode((const unsigned short*)base, smax, semax);
  int i = blockIdx.x * 256 + threadIdx.x;
  if (i >= NNZ) return;
  int id = idx[i];
  float v = load_w(base, id, mode) + alpha[0] * load_w(vals, i, mode);
  Wl[id] = (f16)v;
}

#define SB0 __builtin_amdgcn_sched_barrier(0)
#define VMW(N) asm volatile("s_waitcnt vmcnt(" #N ")" ::: "memory")

// ---------------------------------------------------------------------------
// gemm14b: 256x256, 512 thr = 8 waves as 4M x 2N; wave tile 64 x 128.
// A: fp32, BK=32 quarters [64][32], triple-buffered (96 KiB); wave reads
//    quarter wm only (8 x b128 per tile).
// B: f16, K=64 tiles [64][64] quarters, double-buffered (64 KiB); wave reads
//    quarters 2wn, 2wn+1 (8 x b128 per tile).
// acc[mf][qq*4+nf]: rows wm*64+mf*16, cols wn*128+qq*64+nf*16.
// Tile/gate schedule identical to r23 gemm14.
// ---------------------------------------------------------------------------

#define ISSUE_A14(QI, KT1, AP)                                                 \
    __builtin_amdgcn_global_load_lds(                                          \
        (const AS1 void*)(X + rowOffA[QI] + (KT1) * 32 + swzcA),               \
        (AS3 void*)(&sAf[((AP) * 4 + (QI)) * 2048 + t * 4]), 16, 0, 0)

#define ISSUE_B14(QI, KTB1, BP)                                                \
    __builtin_amdgcn_global_load_lds(                                          \
        (const AS1 void*)(Wl + rowOffB[QI] + (KTB1) * 64 + swzc),              \
        (AS3 void*)(&sB[((BP) * 4 + (QI)) * 4096 + t * 8]), 16, 0, 0)

// A fragments: single quarter wm, 4 m-frags x 2 paired b128 (fp32) + cvt.
#define DSREAD_A14(AP) do {                                                    \
    int qa_ = ((AP) * 4 + wm) * 2048;                                          \
    _Pragma("unroll")                                                          \
    for (int mf_ = 0; mf_ < 4; ++mf_) {                                        \
      int r_ = mf_ * 16 + lr;                                                  \
      f32x4 a0_ = *reinterpret_cast<const f32x4*>(                             \
          &sAf[qa_ + r_ * 32 + (((2 * lk) ^ (r_ & 7)) << 2)]);                 \
      f32x4 a1_ = *reinterpret_cast<const f32x4*>(                             \
          &sAf[qa_ + r_ * 32 + (((2 * lk + 1) ^ (r_ & 7)) << 2)]);             \
      afr[mf_] = (f16x8){(f16)a0_[0], (f16)a0_[1], (f16)a0_[2], (f16)a0_[3],   \
                         (f16)a1_[0], (f16)a1_[1], (f16)a1_[2], (f16)a1_[3]};  \
    }                                                                          \
  } while (0)

// B fragments: two quarters 2wn+qq, 4 n-frags each, k-half S_.
#define DSREAD_B14(BP, S_) do {                                                \
    _Pragma("unroll")                                                          \
    for (int qq_ = 0; qq_ < 2; ++qq_) {                                        \
      int qb_ = ((BP) * 4 + 2 * wn + qq_) * 4096;                              \
      _Pragma("unroll")                                                        \
      for (int nf_ = 0; nf_ < 4; ++nf_) {                                      \
        int r_ = nf_ * 16 + lr;                                                \
        int blk_ = ((S_) * 4 + lk) ^ (lr & 7);                                 \
        bfr[qq_][nf_] = *reinterpret_cast<const f16x8*>(&sB[qb_ + r_ * 64 + blk_ * 8]); \
      }                                                                        \
    }                                                                          \
  } while (0)

#define MFMA32_14 do {                                                         \
    __builtin_amdgcn_s_setprio(1);                                             \
    _Pragma("unroll")                                                          \
    for (int mf_ = 0; mf_ < 4; ++mf_)                                          \
      _Pragma("unroll")                                                        \
      for (int qq_ = 0; qq_ < 2; ++qq_)                                        \
        _Pragma("unroll")                                                      \
        for (int nf_ = 0; nf_ < 4; ++nf_)                                      \
          acc[mf_][qq_ * 4 + nf_] = __builtin_amdgcn_mfma_f32_16x16x32_f16(    \
              afr[mf_], bfr[qq_][nf_], acc[mf_][qq_ * 4 + nf_], 0, 0, 0);      \
    __builtin_amdgcn_s_setprio(0);                                             \
  } while (0)

#define KTILE14(AP, BP, S_, KT, ISSB, ISSA, VMN, GATE) do {                    \
    DSREAD_A14(AP);                                                            \
    DSREAD_B14(BP, S_);                                                        \
    if (ISSB) {                                                                \
      ISSUE_B14(0, ((KT) >> 1) + 1, (((KT) >> 1) + 1) & 1);                    \
      ISSUE_B14(1, ((KT) >> 1) + 1, (((KT) >> 1) + 1) & 1);                    \
      ISSUE_B14(2, ((KT) >> 1) + 1, (((KT) >> 1) + 1) & 1);                    \
      ISSUE_B14(3, ((KT) >> 1) + 1, (((KT) >> 1) + 1) & 1); }                  \
    MFMA32_14;                                                                 \
    if (ISSA) {                                                                \
      ISSUE_A14(0, (KT) + 2, ((KT) + 2) % 3);                                  \
      ISSUE_A14(1, (KT) + 2, ((KT) + 2) % 3);                                  \
      ISSUE_A14(2, (KT) + 2, ((KT) + 2) % 3);                                  \
      ISSUE_A14(3, (KT) + 2, ((KT) + 2) % 3); }                                \
    if (GATE) {                                                                \
      VMW(VMN);                                                                \
      __builtin_amdgcn_s_barrier();  /* WAR(this) + RAW(next), r9 */           \
      SB0;                           /* hoist guard */                         \
    }                                                                          \
  } while (0)

__global__ void __launch_bounds__(512, 2) gemm14b(const float* __restrict__ X,
                                                  const f16* __restrict__ Wl,
                                                  float* __restrict__ C) {
  extern __shared__ char lds[];
  float* sAf = (float*)lds;                    // 3 x 4 x 2048 f32 = 96 KiB
  f16* sB = (f16*)(lds + 98304);               // 2 x 4 x 4096 f16 = 64 KiB

  int bidx = blockIdx.x;
  int q = gridDim.x >> 3;
  int wg = (bidx & 7) * q + (bidx >> 3);
  int mt = wg >> 2, nt = wg & 3;

  int t = threadIdx.x;
  int lane = t & 63;
  int w = t >> 6;
  int wm = w >> 1;           // M quarter (64 rows) == A quarter index
  int wn = w & 1;            // N half (128 cols) == B quarters 2wn, 2wn+1
  int lr = lane & 15;
  int lk = lane >> 4;

  int rS = t >> 3;
  int swzc = (((t & 7) ^ (rS & 7)) << 3);      // f16 units (B)
  int swzcA = (((t & 7) ^ (rS & 7)) << 2);     // f32 units (A)
  size_t rowOffA[4], rowOffB[4];
#pragma unroll
  for (int qi = 0; qi < 4; ++qi) {
    rowOffA[qi] = (size_t)(mt * 256 + qi * 64 + rS) * IN_F;
    rowOffB[qi] = (size_t)(nt * 256 + qi * 64 + rS) * IN_F;
  }

  f16x8 afr[4], bfr[2][4];
  f32x4 acc[4][8];
#pragma unroll
  for (int i = 0; i < 4; ++i)
#pragma unroll
    for (int j = 0; j < 8; ++j)
      acc[i][j] = (f32x4){0.f, 0.f, 0.f, 0.f};

  // prologue: A(0)->buf0, B(0)->bufB0, A(1)->buf1; VMW(4) drains A0+B0,
  // keeps A(1) in flight; barrier (r9).
  ISSUE_A14(0, 0, 0); ISSUE_A14(1, 0, 0); ISSUE_A14(2, 0, 0); ISSUE_A14(3, 0, 0);
  ISSUE_B14(0, 0, 0); ISSUE_B14(1, 0, 0); ISSUE_B14(2, 0, 0); ISSUE_B14(3, 0, 0);
  ISSUE_A14(0, 1, 1); ISSUE_A14(1, 1, 1); ISSUE_A14(2, 1, 1); ISSUE_A14(3, 1, 1);
  VMW(4);
  __builtin_amdgcn_s_barrier();
  SB0;

  // KT: AP=KT%3, BP=(KT>>1)&1, S=KT&1; ISSB: even KT<=28; ISSA: KT<=29;
  // VMN: even 8 / odd 4; KT=30: VMW(0); KT=31: no gate.
  KTILE14(0, 0, 0,  0, true,  true,  8, true);
  KTILE14(1, 0, 1,  1, false, true,  4, true);
  KTILE14(2, 1, 0,  2, true,  true,  8, true);
  KTILE14(0, 1, 1,  3, false, true,  4, true);
  KTILE14(1, 0, 0,  4, true,  true,  8, true);
  KTILE14(2, 0, 1,  5, false, true,  4, true);
  KTILE14(0, 1, 0,  6, true,  true,  8, true);
  KTILE14(1, 1, 1,  7, false, true,  4, true);
  KTILE14(2, 0, 0,  8, true,  true,  8, true);
  KTILE14(0, 0, 1,  9, false, true,  4, true);
  KTILE14(1, 1, 0, 10, true,  true,  8, true);
  KTILE14(2, 1, 1, 11, false, true,  4, true);
  KTILE14(0, 0, 0, 12, true,  true,  8, true);
  KTILE14(1, 0, 1, 13, false, true,  4, true);
  KTILE14(2, 1, 0, 14, true,  true,  8, true);
  KTILE14(0, 1, 1, 15, false, true,  4, true);
  KTILE14(1, 0, 0, 16, true,  true,  8, true);
  KTILE14(2, 0, 1, 17, false, true,  4, true);
  KTILE14(0, 1, 0, 18, true,  true,  8, true);
  KTILE14(1, 1, 1, 19, false, true,  4, true);
  KTILE14(2, 0, 0, 20, true,  true,  8, true);
  KTILE14(0, 0, 1, 21, false, true,  4, true);
  KTILE14(1, 1, 0, 22, true,  true,  8, true);
  KTILE14(2, 1, 1, 23, false, true,  4, true);
  KTILE14(0, 0, 0, 24, true,  true,  8, true);
  KTILE14(1, 0, 1, 25, false, true,  4, true);
  KTILE14(2, 1, 0, 26, true,  true,  8, true);
  KTILE14(0, 1, 1, 27, false, true,  4, true);
  KTILE14(1, 0, 0, 28, true,  true,  8, true);
  KTILE14(2, 0, 1, 29, false, true,  4, true);
  KTILE14(0, 1, 0, 30, false, false, 0, true);
  KTILE14(1, 1, 1, 31, false, false, 0, false);

  // epilogue: D 16x16 layout col=lr, row=lk*4+g.
  // C row = mt*256 + wm*64 + mf*16 + lk*4 + g; col = nt*256 + wn*128 +
  // qq*64 + nf*16 + lr.
  float* Cw = C + (size_t)(mt * 256 + wm * 64 + lk * 4) * OUT_F + nt * 256 + wn * 128 + lr;
#pragma unroll
  for (int mf = 0; mf < 4; ++mf)
#pragma unroll
    for (int j = 0; j < 8; ++j) {
      int qq = j >> 2, nf = j & 3;
#pragma unroll
      for (int g = 0; g < 4; ++g)
        Cw[(size_t)(mf * 16 + g) * OUT_F + qq * 64 + nf * 16] = acc[mf][j][g];
    }
}

// ---------------------------------------------------------------------------
// gemm14 fallback (replay-proven r20-r23, 105 us headline): 2Mx4N original.
// ---------------------------------------------------------------------------

#define DSREAD_A14o(AP) do {                                                   \
    _Pragma("unroll")                                                          \
    for (int qq_ = 0; qq_ < 2; ++qq_) {                                        \
      int qa_ = ((AP) * 4 + wm2 * 2 + qq_) * 2048;                             \
      _Pragma("unroll")                                                        \
      for (int mf_ = 0; mf_ < 4; ++mf_) {                                      \
        int r_ = mf_ * 16 + lr;                                                \
        f32x4 a0_ = *reinterpret_cast<const f32x4*>(                           \
            &sAf[qa_ + r_ * 32 + (((2 * lk) ^ (r_ & 7)) << 2)]);               \
        f32x4 a1_ = *reinterpret_cast<const f32x4*>(                           \
            &sAf[qa_ + r_ * 32 + (((2 * lk + 1) ^ (r_ & 7)) << 2)]);           \
        afro[qq_][mf_] = (f16x8){(f16)a0_[0], (f16)a0_[1], (f16)a0_[2],        \
                                 (f16)a0_[3], (f16)a1_[0], (f16)a1_[1],        \
                                 (f16)a1_[2], (f16)a1_[3]};                    \
      }                                                                        \
    }                                                                          \
  } while (0)

#define DSREAD_B14o(BP, S_) do {                                               \
    int qb_ = ((BP) * 4 + wn2) * 4096;                                         \
    _Pragma("unroll")                                                          \
    for (int nf_ = 0; nf_ < 4; ++nf_) {                                        \
      int r_ = nf_ * 16 + lr;                                                  \
      int blk_ = ((S_) * 4 + lk) ^ (lr & 7);                                   \
      bfro[nf_] = *reinterpret_cast<const f16x8*>(&sB[qb_ + r_ * 64 + blk_ * 8]); \
    }                                                                          \
  } while (0)

#define MFMA32_14o do {                                                        \
    __builtin_amdgcn_s_setprio(1);                                             \
    _Pragma("unroll")                                                          \
    for (int qq_ = 0; qq_ < 2; ++qq_)                                          \
      _Pragma("unroll")                                                        \
      for (int mf_ = 0; mf_ < 4; ++mf_)                                        \
        _Pragma("unroll")                                                      \
        for (int nf_ = 0; nf_ < 4; ++nf_)                                      \
          acco[qq_ * 4 + mf_][nf_] = __builtin_amdgcn_mfma_f32_16x16x32_f16(   \
              afro[qq_][mf_], bfro[nf_], acco[qq_ * 4 + mf_][nf_], 0, 0, 0);   \
    __builtin_amdgcn_s_setprio(0);                                             \
  } while (0)

#define KTILE14o(AP, BP, S_, KT, ISSB, ISSA, VMN, GATE) do {                   \
    DSREAD_A14o(AP);                                                           \
    DSREAD_B14o(BP, S_);                                                       \
    if (ISSB) {                                                                \
      ISSUE_B14(0, ((KT) >> 1) + 1, (((KT) >> 1) + 1) & 1);                    \
      ISSUE_B14(1, ((KT) >> 1) + 1, (((KT) >> 1) + 1) & 1);                    \
      ISSUE_B14(2, ((KT) >> 1) + 1, (((KT) >> 1) + 1) & 1);                    \
      ISSUE_B14(3, ((KT) >> 1) + 1, (((KT) >> 1) + 1) & 1); }                  \
    MFMA32_14o;                                                                \
    if (ISSA) {                                                                \
      ISSUE_A14(0, (KT) + 2, ((KT) + 2) % 3);                                  \
      ISSUE_A14(1, (KT) + 2, ((KT) + 2) % 3);                                  \
      ISSUE_A14(2, (KT) + 2, ((KT) + 2) % 3);                                  \
      ISSUE_A14(3, (KT) + 2, ((KT) + 2) % 3); }                                \
    if (GATE) {                                                                \
      VMW(VMN);                                                                \
      __builtin_amdgcn_s_barrier();                                            \
      SB0;                                                                     \
    }                                                                          \
  } while (0)

__global__ void __launch_bounds__(512, 2) gemm14(const float* __restrict__ X,
                                                 const f16* __restrict__ Wl,
                                                 float* __restrict__ C) {
  extern __shared__ char lds[];
  float* sAf = (float*)lds;
  f16* sB = (f16*)(lds + 98304);

  int bidx = blockIdx.x;
  int q = gridDim.x >> 3;
  int wg = (bidx & 7) * q + (bidx >> 3);
  int mt = wg >> 2, nt = wg & 3;

  int t = threadIdx.x;
  int lane = t & 63;
  int w = t >> 6;
  int wm2 = w >> 2;
  int wn2 = w & 3;
  int lr = lane & 15;
  int lk = lane >> 4;

  int rS = t >> 3;
  int swzc = (((t & 7) ^ (rS & 7)) << 3);
  int swzcA = (((t & 7) ^ (rS & 7)) << 2);
  size_t rowOffA[4], rowOffB[4];
#pragma unroll
  for (int qi = 0; qi < 4; ++qi) {
    rowOffA[qi] = (size_t)(mt * 256 + qi * 64 + rS) * IN_F;
    rowOffB[qi] = (size_t)(nt * 256 + qi * 64 + rS) * IN_F;
  }

  f16x8 afro[2][4], bfro[4];
  f32x4 acco[8][4];
#pragma unroll
  for (int i = 0; i < 8; ++i)
#pragma unroll
    for (int j = 0; j < 4; ++j)
      acco[i][j] = (f32x4){0.f, 0.f, 0.f, 0.f};

  ISSUE_A14(0, 0, 0); ISSUE_A14(1, 0, 0); ISSUE_A14(2, 0, 0); ISSUE_A14(3, 0, 0);
  ISSUE_B14(0, 0, 0); ISSUE_B14(1, 0, 0); ISSUE_B14(2, 0, 0); ISSUE_B14(3, 0, 0);
  ISSUE_A14(0, 1, 1); ISSUE_A14(1, 1, 1); ISSUE_A14(2, 1, 1); ISSUE_A14(3, 1, 1);
  VMW(4);
  __builtin_amdgcn_s_barrier();
  SB0;

  KTILE14o(0, 0, 0,  0, true,  true,  8, true);
  KTILE14o(1, 0, 1,  1, false, true,  4, true);
  KTILE14o(2, 1, 0,  2, true,  true,  8, true);
  KTILE14o(0, 1, 1,  3, false, true,  4, true);
  KTILE14o(1, 0, 0,  4, true,  true,  8, true);
  KTILE14o(2, 0, 1,  5, false, true,  4, true);
  KTILE14o(0, 1, 0,  6, true,  true,  8, true);
  KTILE14o(1, 1, 1,  7, false, true,  4, true);
  KTILE14o(2, 0, 0,  8, true,  true,  8, true);
  KTILE14o(0, 0, 1,  9, false, true,  4, true);
  KTILE14o(1, 1, 0, 10, true,  true,  8, true);
  KTILE14o(2, 1, 1, 11, false, true,  4, true);
  KTILE14o(0, 0, 0, 12, true,  true,  8, true);
  KTILE14o(1, 0, 1, 13, false, true,  4, true);
  KTILE14o(2, 1, 0, 14, true,  true,  8, true);
  KTILE14o(0, 1, 1, 15, false, true,  4, true);
  KTILE14o(1, 0, 0, 16, true,  true,  8, true);
  KTILE14o(2, 0, 1, 17, false, true,  4, true);
  KTILE14o(0, 1, 0, 18, true,  true,  8, true);
  KTILE14o(1, 1, 1, 19, false, true,  4, true);
  KTILE14o(2, 0, 0, 20, true,  true,  8, true);
  KTILE14o(0, 0, 1, 21, false, true,  4, true);
  KTILE14o(1, 1, 0, 22, true,  true,  8, true);
  KTILE14o(2, 1, 1, 23, false, true,  4, true);
  KTILE14o(0, 0, 0, 24, true,  true,  8, true);
  KTILE14o(1, 0, 1, 25, false, true,  4, true);
  KTILE14o(2, 1, 0, 26, true,  true,  8, true);
  KTILE14o(0, 1, 1, 27, false, true,  4, true);
  KTILE14o(1, 0, 0, 28, true,  true,  8, true);
  KTILE14o(2, 0, 1, 29, false, true,  4, true);
  KTILE14o(0, 1, 0, 30, false, false, 0, true);
  KTILE14o(1, 1, 1, 31, false, false, 0, false);

  float* Cw = C + (size_t)(mt * 256 + wm2 * 128 + lk * 4) * OUT_F + nt * 256 + wn2 * 64 + lr;
#pragma unroll
  for (int m = 0; m < 8; ++m) {
    int rowo = (m >> 2) * 64 + (m & 3) * 16;
#pragma unroll
    for (int nf = 0; nf < 4; ++nf)
#pragma unroll
      for (int g = 0; g < 4; ++g)
        Cw[(size_t)(rowo + g) * OUT_F + nf * 16] = acco[m][nf][g];
  }
}

extern "C" void kernel_launch(void* const* d_in, const int* in_sizes, int n_in,
                              void* d_out, int out_size, void* d_ws, size_t ws_size,
                              hipStream_t stream) {
  const float* X = (const float*)d_in[0];
  const void* base = d_in[1];
  const void* vals = d_in[2];
  const int* idx = (const int*)d_in[3];
  const float* alpha = (const float*)d_in[4];
  float* out = (float*)d_out;
  f16* Wl = (f16*)d_ws;                                   // linear W_eff

  int M = in_sizes[0] / IN_F;              // 32768

  prep_base<<<dim3(512), dim3(256), 0, stream>>>(base, Wl);
  prep_scatter<<<dim3(64), dim3(256), 0, stream>>>(base, vals, idx, alpha, Wl);

  hipError_t e = hipFuncSetAttribute(reinterpret_cast<const void*>(&gemm14b),
                                     hipFuncAttributeMaxDynamicSharedMemorySize, 163840);
  if (e == hipSuccess) {
    gemm14b<<<dim3((M / 256) * 4), dim3(512), 163840, stream>>>(X, Wl, out);
  } else {
    (void)hipFuncSetAttribute(reinterpret_cast<const void*>(&gemm14),
                              hipFuncAttributeMaxDynamicSharedMemorySize, 163840);
    gemm14<<<dim3((M / 256) * 4), dim3(512), 163840, stream>>>(X, Wl, out);
  }
}